// Round 2
// baseline (87.381 us; speedup 1.0000x reference)
//
#include <hip/hip_runtime.h>

// BilateralBlur 7x7, sigma_color=0.1 (l1), sigma_space=1.5, reflect pad.
// (B=4, C=3, H=512, W=512) float32.
//
// R2 design:
// - 2 output pixels per thread (x-adjacent): the 8-tap row window union is
//   read once (8 ds_read_b128) and serves both centers (14 tap-uses/row).
//   LDS reads/pixel: 49 -> 28.
// - dy loop ROLLED (7 iters) to cap live VGPRs (~80-100) -> 4-6 waves/SIMD.
//   R1's full 49-tap unroll hoisted ~49 float4 loads -> ~200 VGPR -> 2
//   waves/SIMD -> latency-bound at 84.6us (5x over the ~16us pipe floor).
// - Channels interleaved in 16B LDS slots: 1 tap = 1 ds_read_b128. Lane
//   stride is 32B -> 2-way bank aliasing = free (m136).
// - Spatial kernel UNNORMALIZED (cancels in ratio). exp via
//   __builtin_amdgcn_exp2f with -50*log2(e) pre-folded into one mul.

constexpr int KR  = 3;
constexpr int CH  = 3;
constexpr int IMH = 512, IMW = 512;
constexpr int BX  = 32, BY = 8;      // 256 threads
constexpr int PX  = 2;               // pixels per thread (x)
constexpr int TLW = BX * PX;         // 64-wide output tile
constexpr int TW  = TLW + 2 * KR;    // 70
constexpr int TH  = BY + 2 * KR;     // 14

__device__ __constant__ float c_w1d[7] = {
    0.13533528f, 0.41111229f, 0.80073744f, 1.0f,
    0.80073744f, 0.41111229f, 0.13533528f};

__global__ __launch_bounds__(BX * BY)
void bilateral7_kernel(const float* __restrict__ in, float* __restrict__ out) {
    __shared__ float tile[TH][TW][4];   // [y][x][c], slot 3 = 16B pad

    const int tx = threadIdx.x, ty = threadIdx.y;
    const int x0 = blockIdx.x * TLW, y0 = blockIdx.y * BY;
    const int b  = blockIdx.z;
    const float* __restrict__ inb = in + (size_t)b * CH * IMH * IMW;
    const int tid = ty * BX + tx;

    // Stage tile with reflect indexing; ix fastest -> coalesced dword loads,
    // 16B lane stride on ds_write -> conflict-free.
    #pragma unroll
    for (int c = 0; c < CH; ++c) {
        for (int i = tid; i < TH * TW; i += BX * BY) {
            const int iy = i / TW, ix = i - iy * TW;
            int gy = y0 + iy - KR, gx = x0 + ix - KR;
            gy = gy < 0 ? -gy : (gy >= IMH ? 2 * IMH - 2 - gy : gy);
            gx = gx < 0 ? -gx : (gx >= IMW ? 2 * IMW - 2 - gx : gx);
            tile[iy][ix][c] = inb[(c * IMH + gy) * IMW + gx];
        }
    }
    __syncthreads();

    const int cx = tx * PX;            // tile col of window start for center 0
    const float4 c0 = *(const float4*)&tile[ty + KR][cx + KR][0];
    const float4 c1 = *(const float4*)&tile[ty + KR][cx + KR + 1][0];

    const float wx[7] = {0.13533528f, 0.41111229f, 0.80073744f, 1.0f,
                         0.80073744f, 0.41111229f, 0.13533528f};
    const float NEG50_LOG2E = -72.13475204444817f;   // -50 * log2(e)

    float a0x = 0.f, a0y = 0.f, a0z = 0.f, w0 = 0.f;
    float a1x = 0.f, a1y = 0.f, a1z = 0.f, w1 = 0.f;

    for (int dy = 0; dy < 7; ++dy) {   // ROLLED: caps register pressure
        const float wy = c_w1d[dy];
        const float* row = &tile[ty + dy][cx][0];

        float4 tp[8];
        #pragma unroll
        for (int t = 0; t < 8; ++t) tp[t] = *(const float4*)(row + 4 * t);

        #pragma unroll
        for (int d = 0; d < 7; ++d) {
            const float wrow = wy * wx[d];
            {   // center 0 uses tap d
                const float4 p = tp[d];
                const float l1 = fabsf(p.x - c0.x) + fabsf(p.y - c0.y) + fabsf(p.z - c0.z);
                const float w  = wrow * __builtin_amdgcn_exp2f(l1 * l1 * NEG50_LOG2E);
                a0x = fmaf(p.x, w, a0x); a0y = fmaf(p.y, w, a0y);
                a0z = fmaf(p.z, w, a0z); w0 += w;
            }
            {   // center 1 uses tap d+1
                const float4 p = tp[d + 1];
                const float l1 = fabsf(p.x - c1.x) + fabsf(p.y - c1.y) + fabsf(p.z - c1.z);
                const float w  = wrow * __builtin_amdgcn_exp2f(l1 * l1 * NEG50_LOG2E);
                a1x = fmaf(p.x, w, a1x); a1y = fmaf(p.y, w, a1y);
                a1z = fmaf(p.z, w, a1z); w1 += w;
            }
        }
    }

    const float i0 = 1.0f / w0, i1 = 1.0f / w1;
    const int y = y0 + ty, x = x0 + cx;
    const size_t hw = (size_t)IMH * IMW;
    const size_t base = (size_t)b * CH * hw + (size_t)y * IMW + x;
    *(float2*)&out[base]          = make_float2(a0x * i0, a1x * i1);
    *(float2*)&out[base + hw]     = make_float2(a0y * i0, a1y * i1);
    *(float2*)&out[base + 2 * hw] = make_float2(a0z * i0, a1z * i1);
}

extern "C" void kernel_launch(void* const* d_in, const int* in_sizes, int n_in,
                              void* d_out, int out_size, void* d_ws, size_t ws_size,
                              hipStream_t stream) {
    const float* in  = (const float*)d_in[0];
    float*       out = (float*)d_out;
    const int B = in_sizes[0] / (CH * IMH * IMW);   // 4
    dim3 grid(IMW / TLW, IMH / BY, B);              // (8, 64, 4) = 2048 blocks
    dim3 block(BX, BY, 1);
    bilateral7_kernel<<<grid, block, 0, stream>>>(in, out);
}